// Round 17
// baseline (153.375 us; speedup 1.0000x reference)
//
#include <hip/hip_runtime.h>
#include <hip/hip_bf16.h>
#include <math.h>

#define BS 8192
#define DH 1024
#define DE 256
#define NL 64
#define SBST 224

typedef __attribute__((ext_vector_type(8))) short short8;
typedef __attribute__((ext_vector_type(4))) short short4v;
typedef __attribute__((ext_vector_type(4))) float f32x4;
typedef __attribute__((ext_vector_type(4))) int i32x4;
typedef unsigned short ushort;

__device__ __forceinline__ ushort bf16b(float f){
  unsigned u = __float_as_uint(f);
  unsigned r = (u + 0x7FFFu + ((u >> 16) & 1u)) >> 16;
  return (ushort)r;
}

__device__ __forceinline__ float fexp2(float x){
  float r;
  asm("v_exp_f32 %0, %1" : "=v"(r) : "v"(x));
  return r;
}

__device__ __forceinline__ void gload_lds16(const void* g, void* l){
  __builtin_amdgcn_global_load_lds((const __attribute__((address_space(1))) void*)g,
                                   (__attribute__((address_space(3))) void*)l, 16, 0, 0);
}

// ---- prep: wcvt (b<128) | labelnorm (128..191) | hist + done-reset (b==192) ----
__global__ __launch_bounds__(256) void prep_kernel(const float* __restrict__ W, ushort* __restrict__ Wb,
    const float* __restrict__ label_emb, ushort* __restrict__ lnb,
    const int* __restrict__ labels, int* __restrict__ cnt,
    int* __restrict__ offs, int* __restrict__ groups, int* __restrict__ done){
  int b = blockIdx.x, t = threadIdx.x;
  if (b < 128){
    int i = (b*256 + t) * 8;
    float4 v0 = *(const float4*)(W+i);
    float4 v1 = *(const float4*)(W+i+4);
    short8 o;
    o[0]=bf16b(v0.x); o[1]=bf16b(v0.y); o[2]=bf16b(v0.z); o[3]=bf16b(v0.w);
    o[4]=bf16b(v1.x); o[5]=bf16b(v1.y); o[6]=bf16b(v1.z); o[7]=bf16b(v1.w);
    *(short8*)(Wb+i) = o;
    return;
  }
  if (b < 192){
    __shared__ float red[256];
    int l = b - 128;
    float v = label_emb[l*DE + t];
    red[t] = v*v;
    __syncthreads();
    for (int s=128;s>0;s>>=1){
      if (t<s) red[t] += red[t+s];
      __syncthreads();
    }
    float inv = 1.0f / fmaxf(sqrtf(red[0]), 1e-8f);
    lnb[l*DE + t] = bf16b(v * inv);
    return;
  }
  // b == 192: histogram + stable group scatter (+ reset finalize gate)
  if (t == 0) done[0] = 0;
  __shared__ ushort loc[256][64];
  __shared__ int off_s[65];
  __shared__ int cnt_s[64];
  #pragma unroll
  for (int l=0;l<64;l++) loc[t][l]=0;
  __syncthreads();
  int base = t * 32;
  for (int i=0;i<32;i++){
    int y = labels[base+i];
    loc[t][y] = (ushort)(loc[t][y] + 1);
  }
  __syncthreads();
  if (t < 64){
    int run = 0;
    for (int tt=0;tt<256;tt++){
      int v = loc[tt][t];
      loc[tt][t] = (ushort)run;
      run += v;
    }
    cnt_s[t] = run;
    cnt[t] = run;
  }
  __syncthreads();
  if (t == 0){
    int acc = 0;
    for (int l=0;l<64;l++){ off_s[l] = acc; acc += cnt_s[l]; }
    off_s[64] = acc;
  }
  __syncthreads();
  if (t < 65) offs[t] = off_s[t];
  for (int i=0;i<32;i++){
    int idx = base + i;
    int y = labels[idx];
    int p = off_s[y] + loc[t][y];
    loc[t][y] = (ushort)(loc[t][y] + 1);
    groups[p] = idx;
  }
}

// ---------------- emb: BM=32, BN=256, 512 threads, all-thread A staging, 2-phase dbuf ----------------
#define EMB_LOADA(KB) do { \
  va = *(const float4*)(aptr + (KB)); \
} while(0)

#define EMB_WRITEA(P) do { \
  short4v o; \
  o[0]=bf16b(va.x); o[1]=bf16b(va.y); o[2]=bf16b(va.z); o[3]=bf16b(va.w); \
  *(short4v*)&Ab[P][awr] = o; \
} while(0)

#define EMB_STAGEB(P, KB) do { \
  _Pragma("unroll") \
  for (int q=0;q<4;q++){ \
    int chunk = q*8 + w; \
    int lin = chunk*64 + lane; \
    int row = lin >> 3, cc = lin & 7; \
    int lc = cc ^ (row & 7); \
    gload_lds16(Wb + (size_t)row*DH + (KB) + lc*8, Bb[P] + chunk*512); \
  } \
} while(0)

#define EMB_COMPUTE(P) do { \
  _Pragma("unroll") \
  for (int kk=0;kk<2;kk++){ \
    short8 af[2], bfr[2]; \
    _Pragma("unroll") \
    for (int m=0;m<2;m++){ \
      int row = m*16 + c15; \
      int phys = (kk*4 + qr) ^ (row & 7); \
      af[m] = *(const short8*)&Ab[P][row*64 + phys*8]; \
    } \
    _Pragma("unroll") \
    for (int n=0;n<2;n++){ \
      int row = w*32 + n*16 + c15; \
      int phys = (kk*4 + qr) ^ (row & 7); \
      bfr[n] = *(const short8*)&Bb[P][row*64 + phys*8]; \
    } \
    _Pragma("unroll") \
    for (int m=0;m<2;m++) \
      _Pragma("unroll") \
      for (int n=0;n<2;n++) \
        acc[m][n] = __builtin_amdgcn_mfma_f32_16x16x32_bf16(af[m], bfr[n], acc[m][n], 0,0,0); \
  } \
} while(0)

__global__ __launch_bounds__(512) void emb_kernel(const float* __restrict__ mask,
    const ushort* __restrict__ Wb, const float* __restrict__ bias,
    ushort* __restrict__ enb, signed char* __restrict__ eni8){
  __shared__ ushort Ab[2][32*64];    // 2 x 4KB
  __shared__ ushort Bb[2][256*64];   // 2 x 32KB
  __shared__ float sq[8][32];
  __shared__ float inv_s[32];
  int tid = threadIdx.x, lane = tid & 63, w = tid >> 6;   // 8 waves
  int qr = lane >> 4, c15 = lane & 15;
  int rb = blockIdx.x * 32;
  // all-thread A staging: one float4 per thread
  int arow = tid >> 4, c4 = tid & 15;
  int awr = arow*64 + (((c4>>1) ^ (arow & 7))*8) + (c4 & 1)*4;
  const float* aptr = mask + (size_t)(rb + arow)*DH + c4*4;
  float4 va;
  f32x4 acc[2][2] = {};
  EMB_LOADA(0);
  EMB_WRITEA(0);
  EMB_STAGEB(0, 0);
  __syncthreads();
  int buf = 0;
  for (int kb = 0; kb < 16; kb++){
    if (kb < 15){
      EMB_LOADA((kb+1)*64);
      EMB_STAGEB(buf^1, (kb+1)*64);
    }
    EMB_COMPUTE(buf);
    if (kb < 15) EMB_WRITEA(buf^1);
    __syncthreads();
    buf ^= 1;
  }
  // epilogue: +bias, row sumsq across 8 waves, normalize, write bf16 + i8
  float bv[2];
  #pragma unroll
  for (int n=0;n<2;n++) bv[n] = bias[w*32 + n*16 + c15];
  #pragma unroll
  for (int m=0;m<2;m++){
    #pragma unroll
    for (int r=0;r<4;r++){
      float s = 0.f;
      #pragma unroll
      for (int n=0;n<2;n++){
        float v = acc[m][n][r] + bv[n];
        acc[m][n][r] = v;
        s += v*v;
      }
      #pragma unroll
      for (int msk=8; msk>=1; msk>>=1) s += __shfl_xor(s, msk);
      if (c15 == 0) sq[w][m*16 + qr*4 + r] = s;
    }
  }
  __syncthreads();
  if (tid < 32){
    float s = 0.f;
    #pragma unroll
    for (int q=0;q<8;q++) s += sq[q][tid];
    inv_s[tid] = 1.0f / fmaxf(sqrtf(s), 1e-8f);
  }
  __syncthreads();
  #pragma unroll
  for (int m=0;m<2;m++){
    #pragma unroll
    for (int r=0;r<4;r++){
      int row = m*16 + qr*4 + r;
      float iv = inv_s[row];
      #pragma unroll
      for (int n=0;n<2;n++){
        int col = w*32 + n*16 + c15;
        float v = acc[m][n][r] * iv;
        enb [(size_t)(rb+row)*DE + col] = bf16b(v);
        int q8 = __float2int_rn(v * 127.0f);
        q8 = q8 > 127 ? 127 : (q8 < -127 ? -127 : q8);
        eni8[(size_t)(rb+row)*DE + col] = (signed char)q8;
      }
    }
  }
}

// ---------------- kernel 3: c2(0..127) | gsum(128..383) | npass-i8(384..4479) ----------------
__global__ __launch_bounds__(256, 4) void fused3_kernel(const ushort* __restrict__ enb,
    const signed char* __restrict__ eni8, const ushort* __restrict__ lnb,
    const int* __restrict__ labels, const int* __restrict__ cnt,
    const int* __restrict__ offs, const int* __restrict__ groups,
    float* __restrict__ N_part, float* __restrict__ pos, float* __restrict__ rowsum,
    float* __restrict__ T_part, float* __restrict__ G_part,
    float* __restrict__ samesum, ushort* __restrict__ Sbuf){
  __shared__ __align__(16) char pool[33792];
  int blk = blockIdx.x;
  int tid = threadIdx.x, lane = tid & 63, w = tid >> 6;
  int qr = lane >> 4, c15 = lane & 15;

  if (blk < 128){
    // ---- c2: pos, rowsum, T/G partials (bf16) ----
    ushort* Ab = (ushort*)pool;
    ushort* Bb = (ushort*)(pool + 8192);
    float* TpS = (float*)(pool + 16384);
    float* GpS = (float*)(pool + 17408);
    int rb = blk * 64;
    f32x4 acc[4] = {};
    for (int kb = 0; kb < DE; kb += 64){
      #pragma unroll
      for (int q=0;q<2;q++){
        int chunk = q*4 + w;
        int lin = chunk*64 + lane;
        int row = lin >> 3, cc = lin & 7;
        int lc = cc ^ (row & 7);
        gload_lds16(enb + (size_t)(rb+row)*DE + kb + lc*8, Ab + chunk*512);
      }
      #pragma unroll
      for (int q=0;q<2;q++){
        int chunk = q*4 + w;
        int lin = chunk*64 + lane;
        int row = lin >> 3, cc = lin & 7;
        int lc = cc ^ (row & 7);
        gload_lds16(lnb + (size_t)row*DE + kb + lc*8, Bb + chunk*512);
      }
      __syncthreads();
      #pragma unroll
      for (int kk=0;kk<2;kk++){
        int arow = w*16 + c15;
        int aphys = (kk*4 + (lane >> 4)) ^ (arow & 7);
        short8 af = *(const short8*)&Ab[arow*64 + aphys*8];
        #pragma unroll
        for (int ni=0;ni<4;ni++){
          int brow = ni*16 + c15;
          int bphys = (kk*4 + (lane >> 4)) ^ (brow & 7);
          short8 bfr = *(const short8*)&Bb[brow*64 + bphys*8];
          acc[ni] = __builtin_amdgcn_mfma_f32_16x16x32_bf16(af, bfr, acc[ni], 0,0,0);
        }
      }
      __syncthreads();
    }
    int yr[4];
    #pragma unroll
    for (int r=0;r<4;r++) yr[r] = labels[rb + w*16 + qr*4 + r];
    float e[4][4];
    #pragma unroll
    for (int ni=0;ni<4;ni++)
      #pragma unroll
      for (int r=0;r<4;r++) e[ni][r] = __expf(acc[ni][r]);
    #pragma unroll
    for (int r=0;r<4;r++){
      float rs = e[0][r]+e[1][r]+e[2][r]+e[3][r];
      float ps = 0.f;
      #pragma unroll
      for (int ni=0;ni<4;ni++) if (ni*16 + c15 == yr[r]) ps = acc[ni][r];
      #pragma unroll
      for (int msk=8; msk>=1; msk>>=1){ rs += __shfl_xor(rs, msk); ps += __shfl_xor(ps, msk); }
      if (c15 == 0){
        int grow = rb + w*16 + qr*4 + r;
        rowsum[grow] = rs;
        pos[grow] = ps;
      }
    }
    #pragma unroll
    for (int ni=0;ni<4;ni++){
      int col = ni*16 + c15;
      float t = 0.f, g = 0.f;
      #pragma unroll
      for (int r=0;r<4;r++){
        t += e[ni][r];
        if (col == yr[r]) g += e[ni][r];
      }
      t += __shfl_xor(t, 16); t += __shfl_xor(t, 32);
      g += __shfl_xor(g, 16); g += __shfl_xor(g, 32);
      if (qr == 0){ TpS[w*64 + col] = t; GpS[w*64 + col] = g; }
    }
    __syncthreads();
    if (tid < 64){
      T_part[(size_t)blk*64 + tid] = TpS[tid]+TpS[64+tid]+TpS[128+tid]+TpS[192+tid];
      G_part[(size_t)blk*64 + tid] = GpS[tid]+GpS[64+tid]+GpS[128+tid]+GpS[192+tid];
    }
    return;
  }

  if (blk < 384){
    // ---- gsum: G_a + Sbuf store; swapped-operand MFMA (bf16) ----
    ushort* Ab = (ushort*)pool;                 // 64x64
    ushort* Bb = (ushort*)(pool + 8192);        // 128x64
    int* aidx = (int*)(pool + 24576);
    int* gidx = (int*)(pool + 24832);
    float* Gs = (float*)(pool + 25344);
    int gid = blk - 128;
    int l = gid & 63, rt = gid >> 6;
    int m = cnt[l], off = offs[l];
    ushort* Sl = Sbuf + (size_t)l * SBST * SBST;
    for (int ra = rt*64; ra < m; ra += 256){
      __syncthreads();
      if (tid < 64){ int a = ra + tid; aidx[tid] = groups[off + (a < m ? a : 0)]; }
      float Ga[4] = {0.f,0.f,0.f,0.f};
      for (int cb2 = 0; cb2 < m; cb2 += 128){
        __syncthreads();
        if (tid < 128){ int bb = cb2 + tid; gidx[tid] = groups[off + (bb < m ? bb : 0)]; }
        __syncthreads();
        f32x4 acc[4][2] = {};
        for (int kb = 0; kb < DE; kb += 64){
          #pragma unroll
          for (int q=0;q<2;q++){
            int chunk = q*4 + w;
            int lin = chunk*64 + lane;
            int row = lin >> 3, cc = lin & 7;
            int lc = cc ^ (row & 7);
            gload_lds16(enb + (size_t)aidx[row]*DE + kb + lc*8, Ab + chunk*512);
          }
          #pragma unroll
          for (int q=0;q<4;q++){
            int chunk = q*4 + w;
            int lin = chunk*64 + lane;
            int row = lin >> 3, cc = lin & 7;
            int lc = cc ^ (row & 7);
            gload_lds16(enb + (size_t)gidx[row]*DE + kb + lc*8, Bb + chunk*512);
          }
          __syncthreads();
          #pragma unroll
          for (int kk=0;kk<2;kk++){
            short8 af[4], bfr[2];
            #pragma unroll
            for (int mi=0;mi<4;mi++){
              int row = mi*16 + c15;
              int phys = (kk*4 + (lane >> 4)) ^ (row & 7);
              af[mi] = *(const short8*)&Ab[row*64 + phys*8];
            }
            #pragma unroll
            for (int ni=0;ni<2;ni++){
              int row = w*32 + ni*16 + c15;
              int phys = (kk*4 + (lane >> 4)) ^ (row & 7);
              bfr[ni] = *(const short8*)&Bb[row*64 + phys*8];
            }
            #pragma unroll
            for (int mi=0;mi<4;mi++)
              #pragma unroll
              for (int ni=0;ni<2;ni++)
                acc[mi][ni] = __builtin_amdgcn_mfma_f32_16x16x32_bf16(bfr[ni], af[mi], acc[mi][ni], 0,0,0);
          }
          __syncthreads();
        }
        #pragma unroll
        for (int mi=0;mi<4;mi++){
          int a = ra + mi*16 + c15;
          bool aok = (a < m);
          #pragma unroll
          for (int ni=0;ni<2;ni++){
            int b0 = cb2 + w*32 + ni*16 + qr*4;
            #pragma unroll
            for (int r=0;r<4;r++){
              int bb = b0 + r;
              float sv = acc[mi][ni][r];
              if (bb < m){
                Ga[mi] += __expf(sv);
                if (aok) Sl[(size_t)a*SBST + bb] = bf16b(sv);
              }
            }
          }
        }
      }
      #pragma unroll
      for (int mi=0;mi<4;mi++){
        float g = Ga[mi];
        g += __shfl_xor(g, 16);
        g += __shfl_xor(g, 32);
        if (lane < 16) Gs[w*64 + mi*16 + lane] = g;
      }
      __syncthreads();
      if (tid < 64 && ra + tid < m)
        samesum[aidx[tid]] = Gs[tid] + Gs[64+tid] + Gs[128+tid] + Gs[192+tid];
    }
    return;
  }

  // ---- npass i8: full-S 128x128, 16x16x64 i8 MFMA (swapped operands), XCD swizzle ----
  signed char* Ai = (signed char*)pool;             // 16KB
  signed char* Bi = (signed char*)(pool + 16384);   // 16KB
  float* nred = (float*)(pool + 32768);             // 1KB
  int lin0 = blk - 384;
  int sw = (lin0 & 7) * 512 + (lin0 >> 3);
  int bx = sw & 63, by = sw >> 6;
  int wr = w >> 1, wc = w & 1;
  int rb = bx * 128;
  int cb = by * 128;
  i32x4 acc[4][4] = {};
  for (int kb = 0; kb < 256; kb += 128){
    #pragma unroll
    for (int q=0;q<4;q++){
      int chunk = q*4 + w;
      int lin2 = chunk*64 + lane;
      int row = lin2 >> 3, cc = lin2 & 7;
      int lc = cc ^ (row & 7);
      gload_lds16(eni8 + (size_t)(rb + row)*DE + kb + lc*16, Ai + chunk*1024);
      gload_lds16(eni8 + (size_t)(cb + row)*DE + kb + lc*16, Bi + chunk*1024);
    }
    __syncthreads();
    __builtin_amdgcn_s_setprio(1);
    #pragma unroll
    for (int kk=0;kk<2;kk++){
      i32x4 af[4], bfr[4];
      #pragma unroll
      for (int m=0;m<4;m++){
        int row = wr*64 + m*16 + c15;
        int phys = (kk*4 + qr) ^ (row & 7);
        af[m] = *(const i32x4*)&Ai[row*128 + phys*16];
      }
      #pragma unroll
      for (int n=0;n<4;n++){
        int row = wc*64 + n*16 + c15;
        int phys = (kk*4 + qr) ^ (row & 7);
        bfr[n] = *(const i32x4*)&Bi[row*128 + phys*16];
      }
      #pragma unroll
      for (int m=0;m<4;m++)
        #pragma unroll
        for (int n=0;n<4;n++)
          acc[m][n] = __builtin_amdgcn_mfma_i32_16x16x64_i8(bfr[n], af[m], acc[m][n], 0,0,0);
    }
    __builtin_amdgcn_s_setprio(0);
    __syncthreads();
  }
  const float SC = 1.44269504f / 16129.0f;
  #pragma unroll
  for (int m=0;m<4;m++){
    float s = 0.f;
    #pragma unroll
    for (int n=0;n<4;n++)
      #pragma unroll
      for (int r=0;r<4;r++)
        s += fexp2((float)acc[m][n][r] * SC);
    s += __shfl_xor(s, 16);
    s += __shfl_xor(s, 32);
    if (lane < 16) nred[wc*128 + wr*64 + m*16 + lane] = s;
  }
  __syncthreads();
  if (tid < 128)
    N_part[(size_t)by * BS + rb + tid] = nred[tid] + nred[128 + tid];
}

// ---------------- kernel 4: reduceN(0..31) | pairs(32..543) | last-block finalize ----------------
__global__ __launch_bounds__(256) void tail_kernel(const int* __restrict__ labels,
    const int* __restrict__ cnt, const int* __restrict__ offs,
    const int* __restrict__ groups, const float* __restrict__ N_part,
    const float* __restrict__ samesum, float* __restrict__ Nrow,
    const ushort* __restrict__ Sbuf, float* __restrict__ pairp,
    const float* __restrict__ pos, const float* __restrict__ rowsum,
    const float* __restrict__ T_part, const float* __restrict__ G_part,
    int* __restrict__ done, float* __restrict__ out){
  __shared__ float red[256];
  __shared__ float NaS[32];
  __shared__ int lastS;
  int b = blockIdx.x, tid = threadIdx.x;
  if (b < 32){
    int i = b*256 + tid;
    float s = 0.f;
    #pragma unroll
    for (int c=0;c<64;c++) s += N_part[(size_t)c*BS + i];
    Nrow[i] = s - samesum[i];
  } else {
    int pid = b - 32;
    int l = pid & 63, split = pid >> 6;
    int m = cnt[l], off = offs[l];
    const ushort* Sl = Sbuf + (size_t)l * SBST * SBST;
    int r = tid >> 3, c = tid & 7;
    int a = split*32 + r;
    {
      float s0 = 0.f;
      if (a < m){
        int g = groups[off + a];
        #pragma unroll
        for (int q=0;q<8;q++) s0 += N_part[(size_t)(c + q*8)*BS + g];
      }
      #pragma unroll
      for (int msk=4; msk>=1; msk>>=1) s0 += __shfl_xor(s0, msk);
      if (c == 0 && a < m) NaS[r] = s0 - samesum[groups[off + a]];
    }
    __syncthreads();
    float sum = 0.f;
    if (a < m){
      float Na = NaS[r];
      const ushort* Srow = Sl + (size_t)a * SBST;
      int nseg = (m + 7) >> 3;
      for (int st = c; st < nseg; st += 8){
        short8 v = *(const short8*)(Srow + st*8);
        #pragma unroll
        for (int j=0;j<8;j++){
          int b2 = st*8 + j;
          if (b2 < m && b2 != a){
            float s = __uint_as_float((unsigned)(ushort)v[j] << 16);
            sum += -s + __logf(Na + __expf(s));
          }
        }
      }
    }
    red[tid] = sum;
    __syncthreads();
    for (int s=128;s>0;s>>=1){ if (tid<s) red[tid]+=red[tid+s]; __syncthreads(); }
    if (tid==0) pairp[pid] = red[0];
  }
  // ---- last-block gate -> inline finalize ----
  __syncthreads();
  __threadfence();
  if (tid == 0) lastS = (atomicAdd(done, 1) == 543) ? 1 : 0;
  __syncthreads();
  if (!lastS) return;
  __threadfence();
  {
    __shared__ double dred[3*256];
    __shared__ float TGp[4][64];
    __shared__ float TGf[64];
    int t = tid;
    {
      int l = t & 63, qq = t >> 6;
      float ts = 0.f, gs = 0.f;
      for (int bb=qq; bb<128; bb+=4){ ts += T_part[bb*64 + l]; gs += G_part[bb*64 + l]; }
      TGp[qq][l] = ts - gs;
    }
    __syncthreads();
    if (t < 64) TGf[t] = TGp[0][t]+TGp[1][t]+TGp[2][t]+TGp[3][t];
    __syncthreads();
    double a=0.0, p1=0.0, p2=0.0;
    for (int i=t; i<BS; i+=256){
      int y = labels[i];
      float Ni = Nrow[i];
      a += (double)((float)(BS - cnt[y]) * __logf(Ni + 1.0f));
      float ps = pos[i];
      p1 += (double)(-ps + __logf(rowsum[i]));
      p2 += (double)(-ps + __logf(TGf[y] + __expf(ps)));
    }
    dred[t]=a; dred[256+t]=p1; dred[512+t]=p2;
    __syncthreads();
    for (int s=128;s>0;s>>=1){
      if (t<s){ dred[t]+=dred[t+s]; dred[256+t]+=dred[256+t+s]; dred[512+t]+=dred[512+t+s]; }
      __syncthreads();
    }
    if (t==0){
      double pair = 0.0;
      for (int l=0;l<512;l++) pair += (double)pairp[l];
      double inter = (dred[0] + pair) / ((double)BS * (double)BS);
      double proto = (dred[256] + dred[512]) / (double)BS;
      out[0] = (float)(0.5*inter + 0.5*proto);
    }
  }
}

extern "C" void kernel_launch(void* const* d_in, const int* in_sizes, int n_in,
                              void* d_out, int out_size, void* d_ws, size_t ws_size,
                              hipStream_t stream){
  const float* mask  = (const float*)d_in[0];
  const float* W     = (const float*)d_in[1];
  const float* bias  = (const float*)d_in[2];
  const float* lemb  = (const float*)d_in[3];
  const int*   labels= (const int*)d_in[4];
  float* out = (float*)d_out;

  ushort* enb    = (ushort*)d_ws;                   // 8192*256 bf16 (4MB)
  signed char* eni8 = (signed char*)(enb + (size_t)BS*DE);  // 8192*256 i8 (2MB)
  ushort* Wb     = (ushort*)(eni8 + (size_t)BS*DE); // 256*1024 bf16
  ushort* lnb    = Wb + (size_t)DE*DH;              // 64*256 bf16
  ushort* Sbuf   = lnb + (size_t)NL*DE;             // 64*224*224 bf16
  float*  N_part = (float*)(Sbuf + (size_t)NL*SBST*SBST);  // 64*8192
  float*  Nrow   = N_part + (size_t)64*BS;          // 8192
  float*  pos    = Nrow + BS;                       // 8192
  float*  rowsum = pos + BS;                        // 8192
  float*  samesum= rowsum + BS;                     // 8192
  float*  T_part = samesum + BS;                    // 128*64
  float*  G_part = T_part + 128*64;                 // 128*64
  float*  pairp  = G_part + 128*64;                 // 512
  int* cnt    = (int*)(pairp + 512);                // 64
  int* offs   = cnt + NL;                           // 65 (pad 68)
  int* groups = offs + 68;                          // 8192
  int* done   = groups + BS;                        // 1

  hipLaunchKernelGGL(prep_kernel,     dim3(193), dim3(256), 0, stream, W, Wb, lemb, lnb, labels, cnt, offs, groups, done);
  hipLaunchKernelGGL(emb_kernel,      dim3(BS/32), dim3(512), 0, stream, mask, Wb, bias, enb, eni8);
  hipLaunchKernelGGL(fused3_kernel,   dim3(4480), dim3(256), 0, stream,
                     enb, eni8, lnb, labels, cnt, offs, groups,
                     N_part, pos, rowsum, T_part, G_part, samesum, Sbuf);
  hipLaunchKernelGGL(tail_kernel,     dim3(544), dim3(256), 0, stream,
                     labels, cnt, offs, groups, N_part, samesum, Nrow, Sbuf, pairp,
                     pos, rowsum, T_part, G_part, done, out);
}

// Round 18
// 114.158 us; speedup vs baseline: 1.3435x; 1.3435x over previous
//
#include <hip/hip_runtime.h>
#include <hip/hip_bf16.h>
#include <math.h>

#define BS 8192
#define DH 1024
#define DE 256
#define NL 64
#define SBST 224

typedef __attribute__((ext_vector_type(8))) short short8;
typedef __attribute__((ext_vector_type(4))) short short4v;
typedef __attribute__((ext_vector_type(4))) float f32x4;
typedef __attribute__((ext_vector_type(4))) int i32x4;
typedef unsigned short ushort;

__device__ __forceinline__ ushort bf16b(float f){
  unsigned u = __float_as_uint(f);
  unsigned r = (u + 0x7FFFu + ((u >> 16) & 1u)) >> 16;
  return (ushort)r;
}

__device__ __forceinline__ float fexp2(float x){
  float r;
  asm("v_exp_f32 %0, %1" : "=v"(r) : "v"(x));
  return r;
}

__device__ __forceinline__ void gload_lds16(const void* g, void* l){
  __builtin_amdgcn_global_load_lds((const __attribute__((address_space(1))) void*)g,
                                   (__attribute__((address_space(3))) void*)l, 16, 0, 0);
}

// ---- prep: wcvt (b<128) | labelnorm (128..191) | hist (b==192) ----
__global__ __launch_bounds__(256) void prep_kernel(const float* __restrict__ W, ushort* __restrict__ Wb,
    const float* __restrict__ label_emb, ushort* __restrict__ lnb,
    const int* __restrict__ labels, int* __restrict__ cnt,
    int* __restrict__ offs, int* __restrict__ groups){
  int b = blockIdx.x, t = threadIdx.x;
  if (b < 128){
    int i = (b*256 + t) * 8;
    float4 v0 = *(const float4*)(W+i);
    float4 v1 = *(const float4*)(W+i+4);
    short8 o;
    o[0]=bf16b(v0.x); o[1]=bf16b(v0.y); o[2]=bf16b(v0.z); o[3]=bf16b(v0.w);
    o[4]=bf16b(v1.x); o[5]=bf16b(v1.y); o[6]=bf16b(v1.z); o[7]=bf16b(v1.w);
    *(short8*)(Wb+i) = o;
    return;
  }
  if (b < 192){
    __shared__ float red[256];
    int l = b - 128;
    float v = label_emb[l*DE + t];
    red[t] = v*v;
    __syncthreads();
    for (int s=128;s>0;s>>=1){
      if (t<s) red[t] += red[t+s];
      __syncthreads();
    }
    float inv = 1.0f / fmaxf(sqrtf(red[0]), 1e-8f);
    lnb[l*DE + t] = bf16b(v * inv);
    return;
  }
  // b == 192: histogram + stable group scatter
  __shared__ ushort loc[256][64];
  __shared__ int off_s[65];
  __shared__ int cnt_s[64];
  #pragma unroll
  for (int l=0;l<64;l++) loc[t][l]=0;
  __syncthreads();
  int base = t * 32;
  for (int i=0;i<32;i++){
    int y = labels[base+i];
    loc[t][y] = (ushort)(loc[t][y] + 1);
  }
  __syncthreads();
  if (t < 64){
    int run = 0;
    for (int tt=0;tt<256;tt++){
      int v = loc[tt][t];
      loc[tt][t] = (ushort)run;
      run += v;
    }
    cnt_s[t] = run;
    cnt[t] = run;
  }
  __syncthreads();
  if (t == 0){
    int acc = 0;
    for (int l=0;l<64;l++){ off_s[l] = acc; acc += cnt_s[l]; }
    off_s[64] = acc;
  }
  __syncthreads();
  if (t < 65) offs[t] = off_s[t];
  for (int i=0;i<32;i++){
    int idx = base + i;
    int y = labels[idx];
    int p = off_s[y] + loc[t][y];
    loc[t][y] = (ushort)(loc[t][y] + 1);
    groups[p] = idx;
  }
}

// ---------------- emb: BM=32, BN=256, 512 threads, all-thread A staging, 2-phase dbuf ----------------
#define EMB_LOADA(KB) do { \
  va = *(const float4*)(aptr + (KB)); \
} while(0)

#define EMB_WRITEA(P) do { \
  short4v o; \
  o[0]=bf16b(va.x); o[1]=bf16b(va.y); o[2]=bf16b(va.z); o[3]=bf16b(va.w); \
  *(short4v*)&Ab[P][awr] = o; \
} while(0)

#define EMB_STAGEB(P, KB) do { \
  _Pragma("unroll") \
  for (int q=0;q<4;q++){ \
    int chunk = q*8 + w; \
    int lin = chunk*64 + lane; \
    int row = lin >> 3, cc = lin & 7; \
    int lc = cc ^ (row & 7); \
    gload_lds16(Wb + (size_t)row*DH + (KB) + lc*8, Bb[P] + chunk*512); \
  } \
} while(0)

#define EMB_COMPUTE(P) do { \
  _Pragma("unroll") \
  for (int kk=0;kk<2;kk++){ \
    short8 af[2], bfr[2]; \
    _Pragma("unroll") \
    for (int m=0;m<2;m++){ \
      int row = m*16 + c15; \
      int phys = (kk*4 + qr) ^ (row & 7); \
      af[m] = *(const short8*)&Ab[P][row*64 + phys*8]; \
    } \
    _Pragma("unroll") \
    for (int n=0;n<2;n++){ \
      int row = w*32 + n*16 + c15; \
      int phys = (kk*4 + qr) ^ (row & 7); \
      bfr[n] = *(const short8*)&Bb[P][row*64 + phys*8]; \
    } \
    _Pragma("unroll") \
    for (int m=0;m<2;m++) \
      _Pragma("unroll") \
      for (int n=0;n<2;n++) \
        acc[m][n] = __builtin_amdgcn_mfma_f32_16x16x32_bf16(af[m], bfr[n], acc[m][n], 0,0,0); \
  } \
} while(0)

__global__ __launch_bounds__(512) void emb_kernel(const float* __restrict__ mask,
    const ushort* __restrict__ Wb, const float* __restrict__ bias,
    ushort* __restrict__ enb, signed char* __restrict__ eni8){
  __shared__ ushort Ab[2][32*64];    // 2 x 4KB
  __shared__ ushort Bb[2][256*64];   // 2 x 32KB
  __shared__ float sq[8][32];
  __shared__ float inv_s[32];
  int tid = threadIdx.x, lane = tid & 63, w = tid >> 6;   // 8 waves
  int qr = lane >> 4, c15 = lane & 15;
  int rb = blockIdx.x * 32;
  // all-thread A staging: one float4 per thread
  int arow = tid >> 4, c4 = tid & 15;
  int awr = arow*64 + (((c4>>1) ^ (arow & 7))*8) + (c4 & 1)*4;
  const float* aptr = mask + (size_t)(rb + arow)*DH + c4*4;
  float4 va;
  f32x4 acc[2][2] = {};
  EMB_LOADA(0);
  EMB_WRITEA(0);
  EMB_STAGEB(0, 0);
  __syncthreads();
  int buf = 0;
  for (int kb = 0; kb < 16; kb++){
    if (kb < 15){
      EMB_LOADA((kb+1)*64);
      EMB_STAGEB(buf^1, (kb+1)*64);
    }
    EMB_COMPUTE(buf);
    if (kb < 15) EMB_WRITEA(buf^1);
    __syncthreads();
    buf ^= 1;
  }
  // epilogue: +bias, row sumsq across 8 waves, normalize, write bf16 + i8
  float bv[2];
  #pragma unroll
  for (int n=0;n<2;n++) bv[n] = bias[w*32 + n*16 + c15];
  #pragma unroll
  for (int m=0;m<2;m++){
    #pragma unroll
    for (int r=0;r<4;r++){
      float s = 0.f;
      #pragma unroll
      for (int n=0;n<2;n++){
        float v = acc[m][n][r] + bv[n];
        acc[m][n][r] = v;
        s += v*v;
      }
      #pragma unroll
      for (int msk=8; msk>=1; msk>>=1) s += __shfl_xor(s, msk);
      if (c15 == 0) sq[w][m*16 + qr*4 + r] = s;
    }
  }
  __syncthreads();
  if (tid < 32){
    float s = 0.f;
    #pragma unroll
    for (int q=0;q<8;q++) s += sq[q][tid];
    inv_s[tid] = 1.0f / fmaxf(sqrtf(s), 1e-8f);
  }
  __syncthreads();
  #pragma unroll
  for (int m=0;m<2;m++){
    #pragma unroll
    for (int r=0;r<4;r++){
      int row = m*16 + qr*4 + r;
      float iv = inv_s[row];
      #pragma unroll
      for (int n=0;n<2;n++){
        int col = w*32 + n*16 + c15;
        float v = acc[m][n][r] * iv;
        enb [(size_t)(rb+row)*DE + col] = bf16b(v);
        int q8 = __float2int_rn(v * 127.0f);
        q8 = q8 > 127 ? 127 : (q8 < -127 ? -127 : q8);
        eni8[(size_t)(rb+row)*DE + col] = (signed char)q8;
      }
    }
  }
}

// ---------------- kernel 3: c2(0..127) | gsum(128..383) | npass-i8(384..4479) ----------------
__global__ __launch_bounds__(256, 4) void fused3_kernel(const ushort* __restrict__ enb,
    const signed char* __restrict__ eni8, const ushort* __restrict__ lnb,
    const int* __restrict__ labels, const int* __restrict__ cnt,
    const int* __restrict__ offs, const int* __restrict__ groups,
    float* __restrict__ N_part, float* __restrict__ pos, float* __restrict__ rowsum,
    float* __restrict__ T_part, float* __restrict__ G_part,
    float* __restrict__ samesum, ushort* __restrict__ Sbuf){
  __shared__ __align__(16) char pool[33792];
  int blk = blockIdx.x;
  int tid = threadIdx.x, lane = tid & 63, w = tid >> 6;
  int qr = lane >> 4, c15 = lane & 15;

  if (blk < 128){
    // ---- c2: pos, rowsum, T/G partials (bf16) ----
    ushort* Ab = (ushort*)pool;
    ushort* Bb = (ushort*)(pool + 8192);
    float* TpS = (float*)(pool + 16384);
    float* GpS = (float*)(pool + 17408);
    int rb = blk * 64;
    f32x4 acc[4] = {};
    for (int kb = 0; kb < DE; kb += 64){
      #pragma unroll
      for (int q=0;q<2;q++){
        int chunk = q*4 + w;
        int lin = chunk*64 + lane;
        int row = lin >> 3, cc = lin & 7;
        int lc = cc ^ (row & 7);
        gload_lds16(enb + (size_t)(rb+row)*DE + kb + lc*8, Ab + chunk*512);
      }
      #pragma unroll
      for (int q=0;q<2;q++){
        int chunk = q*4 + w;
        int lin = chunk*64 + lane;
        int row = lin >> 3, cc = lin & 7;
        int lc = cc ^ (row & 7);
        gload_lds16(lnb + (size_t)row*DE + kb + lc*8, Bb + chunk*512);
      }
      __syncthreads();
      #pragma unroll
      for (int kk=0;kk<2;kk++){
        int arow = w*16 + c15;
        int aphys = (kk*4 + (lane >> 4)) ^ (arow & 7);
        short8 af = *(const short8*)&Ab[arow*64 + aphys*8];
        #pragma unroll
        for (int ni=0;ni<4;ni++){
          int brow = ni*16 + c15;
          int bphys = (kk*4 + (lane >> 4)) ^ (brow & 7);
          short8 bfr = *(const short8*)&Bb[brow*64 + bphys*8];
          acc[ni] = __builtin_amdgcn_mfma_f32_16x16x32_bf16(af, bfr, acc[ni], 0,0,0);
        }
      }
      __syncthreads();
    }
    int yr[4];
    #pragma unroll
    for (int r=0;r<4;r++) yr[r] = labels[rb + w*16 + qr*4 + r];
    float e[4][4];
    #pragma unroll
    for (int ni=0;ni<4;ni++)
      #pragma unroll
      for (int r=0;r<4;r++) e[ni][r] = __expf(acc[ni][r]);
    #pragma unroll
    for (int r=0;r<4;r++){
      float rs = e[0][r]+e[1][r]+e[2][r]+e[3][r];
      float ps = 0.f;
      #pragma unroll
      for (int ni=0;ni<4;ni++) if (ni*16 + c15 == yr[r]) ps = acc[ni][r];
      #pragma unroll
      for (int msk=8; msk>=1; msk>>=1){ rs += __shfl_xor(rs, msk); ps += __shfl_xor(ps, msk); }
      if (c15 == 0){
        int grow = rb + w*16 + qr*4 + r;
        rowsum[grow] = rs;
        pos[grow] = ps;
      }
    }
    #pragma unroll
    for (int ni=0;ni<4;ni++){
      int col = ni*16 + c15;
      float t = 0.f, g = 0.f;
      #pragma unroll
      for (int r=0;r<4;r++){
        t += e[ni][r];
        if (col == yr[r]) g += e[ni][r];
      }
      t += __shfl_xor(t, 16); t += __shfl_xor(t, 32);
      g += __shfl_xor(g, 16); g += __shfl_xor(g, 32);
      if (qr == 0){ TpS[w*64 + col] = t; GpS[w*64 + col] = g; }
    }
    __syncthreads();
    if (tid < 64){
      T_part[(size_t)blk*64 + tid] = TpS[tid]+TpS[64+tid]+TpS[128+tid]+TpS[192+tid];
      G_part[(size_t)blk*64 + tid] = GpS[tid]+GpS[64+tid]+GpS[128+tid]+GpS[192+tid];
    }
    return;
  }

  if (blk < 384){
    // ---- gsum: G_a + Sbuf store; swapped-operand MFMA (bf16) ----
    ushort* Ab = (ushort*)pool;                 // 64x64
    ushort* Bb = (ushort*)(pool + 8192);        // 128x64
    int* aidx = (int*)(pool + 24576);
    int* gidx = (int*)(pool + 24832);
    float* Gs = (float*)(pool + 25344);
    int gid = blk - 128;
    int l = gid & 63, rt = gid >> 6;
    int m = cnt[l], off = offs[l];
    ushort* Sl = Sbuf + (size_t)l * SBST * SBST;
    for (int ra = rt*64; ra < m; ra += 256){
      __syncthreads();
      if (tid < 64){ int a = ra + tid; aidx[tid] = groups[off + (a < m ? a : 0)]; }
      float Ga[4] = {0.f,0.f,0.f,0.f};
      for (int cb2 = 0; cb2 < m; cb2 += 128){
        __syncthreads();
        if (tid < 128){ int bb = cb2 + tid; gidx[tid] = groups[off + (bb < m ? bb : 0)]; }
        __syncthreads();
        f32x4 acc[4][2] = {};
        for (int kb = 0; kb < DE; kb += 64){
          #pragma unroll
          for (int q=0;q<2;q++){
            int chunk = q*4 + w;
            int lin = chunk*64 + lane;
            int row = lin >> 3, cc = lin & 7;
            int lc = cc ^ (row & 7);
            gload_lds16(enb + (size_t)aidx[row]*DE + kb + lc*8, Ab + chunk*512);
          }
          #pragma unroll
          for (int q=0;q<4;q++){
            int chunk = q*4 + w;
            int lin = chunk*64 + lane;
            int row = lin >> 3, cc = lin & 7;
            int lc = cc ^ (row & 7);
            gload_lds16(enb + (size_t)gidx[row]*DE + kb + lc*8, Bb + chunk*512);
          }
          __syncthreads();
          #pragma unroll
          for (int kk=0;kk<2;kk++){
            short8 af[4], bfr[2];
            #pragma unroll
            for (int mi=0;mi<4;mi++){
              int row = mi*16 + c15;
              int phys = (kk*4 + (lane >> 4)) ^ (row & 7);
              af[mi] = *(const short8*)&Ab[row*64 + phys*8];
            }
            #pragma unroll
            for (int ni=0;ni<2;ni++){
              int row = w*32 + ni*16 + c15;
              int phys = (kk*4 + (lane >> 4)) ^ (row & 7);
              bfr[ni] = *(const short8*)&Bb[row*64 + phys*8];
            }
            #pragma unroll
            for (int mi=0;mi<4;mi++)
              #pragma unroll
              for (int ni=0;ni<2;ni++)
                acc[mi][ni] = __builtin_amdgcn_mfma_f32_16x16x32_bf16(bfr[ni], af[mi], acc[mi][ni], 0,0,0);
          }
          __syncthreads();
        }
        #pragma unroll
        for (int mi=0;mi<4;mi++){
          int a = ra + mi*16 + c15;
          bool aok = (a < m);
          #pragma unroll
          for (int ni=0;ni<2;ni++){
            int b0 = cb2 + w*32 + ni*16 + qr*4;
            #pragma unroll
            for (int r=0;r<4;r++){
              int bb = b0 + r;
              float sv = acc[mi][ni][r];
              if (bb < m){
                Ga[mi] += __expf(sv);
                if (aok) Sl[(size_t)a*SBST + bb] = bf16b(sv);
              }
            }
          }
        }
      }
      #pragma unroll
      for (int mi=0;mi<4;mi++){
        float g = Ga[mi];
        g += __shfl_xor(g, 16);
        g += __shfl_xor(g, 32);
        if (lane < 16) Gs[w*64 + mi*16 + lane] = g;
      }
      __syncthreads();
      if (tid < 64 && ra + tid < m)
        samesum[aidx[tid]] = Gs[tid] + Gs[64+tid] + Gs[128+tid] + Gs[192+tid];
    }
    return;
  }

  // ---- npass i8: full-S 128x128, 16x16x64 i8 MFMA (swapped operands), XCD swizzle ----
  signed char* Ai = (signed char*)pool;             // 16KB
  signed char* Bi = (signed char*)(pool + 16384);   // 16KB
  float* nred = (float*)(pool + 32768);             // 1KB
  int lin0 = blk - 384;
  int sw = (lin0 & 7) * 512 + (lin0 >> 3);
  int bx = sw & 63, by = sw >> 6;
  int wr = w >> 1, wc = w & 1;
  int rb = bx * 128;
  int cb = by * 128;
  i32x4 acc[4][4] = {};
  for (int kb = 0; kb < 256; kb += 128){
    #pragma unroll
    for (int q=0;q<4;q++){
      int chunk = q*4 + w;
      int lin2 = chunk*64 + lane;
      int row = lin2 >> 3, cc = lin2 & 7;
      int lc = cc ^ (row & 7);
      gload_lds16(eni8 + (size_t)(rb + row)*DE + kb + lc*16, Ai + chunk*1024);
      gload_lds16(eni8 + (size_t)(cb + row)*DE + kb + lc*16, Bi + chunk*1024);
    }
    __syncthreads();
    __builtin_amdgcn_s_setprio(1);
    #pragma unroll
    for (int kk=0;kk<2;kk++){
      i32x4 af[4], bfr[4];
      #pragma unroll
      for (int m=0;m<4;m++){
        int row = wr*64 + m*16 + c15;
        int phys = (kk*4 + qr) ^ (row & 7);
        af[m] = *(const i32x4*)&Ai[row*128 + phys*16];
      }
      #pragma unroll
      for (int n=0;n<4;n++){
        int row = wc*64 + n*16 + c15;
        int phys = (kk*4 + qr) ^ (row & 7);
        bfr[n] = *(const i32x4*)&Bi[row*128 + phys*16];
      }
      #pragma unroll
      for (int m=0;m<4;m++)
        #pragma unroll
        for (int n=0;n<4;n++)
          acc[m][n] = __builtin_amdgcn_mfma_i32_16x16x64_i8(bfr[n], af[m], acc[m][n], 0,0,0);
    }
    __builtin_amdgcn_s_setprio(0);
    __syncthreads();
  }
  const float SC = 1.44269504f / 16129.0f;
  #pragma unroll
  for (int m=0;m<4;m++){
    float s = 0.f;
    #pragma unroll
    for (int n=0;n<4;n++)
      #pragma unroll
      for (int r=0;r<4;r++)
        s += fexp2((float)acc[m][n][r] * SC);
    s += __shfl_xor(s, 16);
    s += __shfl_xor(s, 32);
    if (lane < 16) nred[wc*128 + wr*64 + m*16 + lane] = s;
  }
  __syncthreads();
  if (tid < 128)
    N_part[(size_t)by * BS + rb + tid] = nred[tid] + nred[128 + tid];
}

// ---------------- kernel 4: reduceN(0..31) | pairs(32..543: 64 labels x 8 splits) ----------------
__global__ __launch_bounds__(256) void tail_kernel(const int* __restrict__ cnt,
    const int* __restrict__ offs, const int* __restrict__ groups,
    const float* __restrict__ N_part, const float* __restrict__ samesum,
    float* __restrict__ Nrow, const ushort* __restrict__ Sbuf,
    float* __restrict__ pairp){
  __shared__ float red[256];
  __shared__ float NaS[32];
  int b = blockIdx.x, tid = threadIdx.x;
  if (b < 32){
    int i = b*256 + tid;
    float s = 0.f;
    #pragma unroll
    for (int c=0;c<64;c++) s += N_part[(size_t)c*BS + i];
    Nrow[i] = s - samesum[i];
    return;
  }
  int pid = b - 32;
  int l = pid & 63, split = pid >> 6;
  int m = cnt[l], off = offs[l];
  const ushort* Sl = Sbuf + (size_t)l * SBST * SBST;
  int r = tid >> 3, c = tid & 7;
  int a = split*32 + r;
  {
    float s0 = 0.f;
    if (a < m){
      int g = groups[off + a];
      #pragma unroll
      for (int q=0;q<8;q++) s0 += N_part[(size_t)(c + q*8)*BS + g];
    }
    #pragma unroll
    for (int msk=4; msk>=1; msk>>=1) s0 += __shfl_xor(s0, msk);
    if (c == 0 && a < m) NaS[r] = s0 - samesum[groups[off + a]];
  }
  __syncthreads();
  float sum = 0.f;
  if (a < m){
    float Na = NaS[r];
    const ushort* Srow = Sl + (size_t)a * SBST;
    int nseg = (m + 7) >> 3;
    for (int st = c; st < nseg; st += 8){
      short8 v = *(const short8*)(Srow + st*8);
      #pragma unroll
      for (int j=0;j<8;j++){
        int b2 = st*8 + j;
        if (b2 < m && b2 != a){
          float s = __uint_as_float((unsigned)(ushort)v[j] << 16);
          sum += -s + __logf(Na + __expf(s));
        }
      }
    }
  }
  red[tid] = sum;
  __syncthreads();
  for (int s=128;s>0;s>>=1){ if (tid<s) red[tid]+=red[tid+s]; __syncthreads(); }
  if (tid==0) pairp[pid] = red[0];
}

// ---------------- kernel 5: final scalar assembly ----------------
__global__ void finalize_kernel(const int* __restrict__ labels, const int* __restrict__ cnt,
    const float* __restrict__ Nrow, const float* __restrict__ pos,
    const float* __restrict__ rowsum, const float* __restrict__ T_part,
    const float* __restrict__ G_part, const float* __restrict__ pairp,
    float* __restrict__ out){
  __shared__ double red[3*256];
  __shared__ float TGp[4][64];
  __shared__ float TGf[64];
  int t = threadIdx.x;
  {
    int l = t & 63, qq = t >> 6;
    float ts = 0.f, gs = 0.f;
    for (int b=qq; b<128; b+=4){ ts += T_part[b*64 + l]; gs += G_part[b*64 + l]; }
    TGp[qq][l] = ts - gs;
  }
  __syncthreads();
  if (t < 64) TGf[t] = TGp[0][t]+TGp[1][t]+TGp[2][t]+TGp[3][t];
  __syncthreads();
  double a=0.0, p1=0.0, p2=0.0;
  for (int i=t; i<BS; i+=256){
    int y = labels[i];
    float Ni = Nrow[i];
    a += (double)((float)(BS - cnt[y]) * __logf(Ni + 1.0f));
    float ps = pos[i];
    p1 += (double)(-ps + __logf(rowsum[i]));
    p2 += (double)(-ps + __logf(TGf[y] + __expf(ps)));
  }
  red[t]=a; red[256+t]=p1; red[512+t]=p2;
  __syncthreads();
  for (int s=128;s>0;s>>=1){
    if (t<s){ red[t]+=red[t+s]; red[256+t]+=red[256+t+s]; red[512+t]+=red[512+t+s]; }
    __syncthreads();
  }
  if (t==0){
    double pair = 0.0;
    for (int l=0;l<512;l++) pair += (double)pairp[l];
    double inter = (red[0] + pair) / ((double)BS * (double)BS);
    double proto = (red[256] + red[512]) / (double)BS;
    out[0] = (float)(0.5*inter + 0.5*proto);
  }
}

extern "C" void kernel_launch(void* const* d_in, const int* in_sizes, int n_in,
                              void* d_out, int out_size, void* d_ws, size_t ws_size,
                              hipStream_t stream){
  const float* mask  = (const float*)d_in[0];
  const float* W     = (const float*)d_in[1];
  const float* bias  = (const float*)d_in[2];
  const float* lemb  = (const float*)d_in[3];
  const int*   labels= (const int*)d_in[4];
  float* out = (float*)d_out;

  ushort* enb    = (ushort*)d_ws;                   // 8192*256 bf16 (4MB)
  signed char* eni8 = (signed char*)(enb + (size_t)BS*DE);  // 8192*256 i8 (2MB)
  ushort* Wb     = (ushort*)(eni8 + (size_t)BS*DE); // 256*1024 bf16
  ushort* lnb    = Wb + (size_t)DE*DH;              // 64*256 bf16
  ushort* Sbuf   = lnb + (size_t)NL*DE;             // 64*224*224 bf16
  float*  N_part = (float*)(Sbuf + (size_t)NL*SBST*SBST);  // 64*8192
  float*  Nrow   = N_part + (size_t)64*BS;          // 8192
  float*  pos    = Nrow + BS;                       // 8192
  float*  rowsum = pos + BS;                        // 8192
  float*  samesum= rowsum + BS;                     // 8192
  float*  T_part = samesum + BS;                    // 128*64
  float*  G_part = T_part + 128*64;                 // 128*64
  float*  pairp  = G_part + 128*64;                 // 512
  int* cnt    = (int*)(pairp + 512);                // 64
  int* offs   = cnt + NL;                           // 65 (pad 68)
  int* groups = offs + 68;                          // 8192

  hipLaunchKernelGGL(prep_kernel,     dim3(193), dim3(256), 0, stream, W, Wb, lemb, lnb, labels, cnt, offs, groups);
  hipLaunchKernelGGL(emb_kernel,      dim3(BS/32), dim3(512), 0, stream, mask, Wb, bias, enb, eni8);
  hipLaunchKernelGGL(fused3_kernel,   dim3(4480), dim3(256), 0, stream,
                     enb, eni8, lnb, labels, cnt, offs, groups,
                     N_part, pos, rowsum, T_part, G_part, samesum, Sbuf);
  hipLaunchKernelGGL(tail_kernel,     dim3(544), dim3(256), 0, stream,
                     cnt, offs, groups, N_part, samesum, Nrow, Sbuf, pairp);
  hipLaunchKernelGGL(finalize_kernel, dim3(1), dim3(256), 0, stream,
                     labels, cnt, Nrow, pos, rowsum, T_part, G_part, pairp, out);
}